// Round 1
// baseline (1012.627 us; speedup 1.0000x reference)
//
#include <hip/hip_runtime.h>
#include <hip/hip_bf16.h>
#include <cstdint>

// Problem dims (fixed by reference)
#define B_  8
#define C_  256
#define V_  256
#define T_  64
#define CQ_ 32
#define C1_ 128

typedef float  floatx4 __attribute__((ext_vector_type(4)));
typedef __bf16 bf16x8  __attribute__((ext_vector_type(8)));

static __device__ __forceinline__ ushort f2bf(float f) {
    union { float f; uint32_t u; } cv; cv.f = f;
    const uint32_t u = cv.u;
    return (ushort)((u + 0x7FFFu + ((u >> 16) & 1u)) >> 16);   // RNE
}

// ---------------------------------------------------------------------------
// transpose_x: x fp32 [B,C,V,T] -> xT bf16 [B,V,T,C] (channel-contiguous)
// ---------------------------------------------------------------------------
__global__ __launch_bounds__(256) void transpose_x(
    const float* __restrict__ x, ushort* __restrict__ xT)
{
    __shared__ float xs[256 * 65];   // [c][t], row pad 65 -> conflict-free
    const int tid = threadIdx.x;
    const int v = blockIdx.x & 255;
    const int b = blockIdx.x >> 8;

    for (int i = tid; i < 16384; i += 256) {
        const int t = i & 63, c = i >> 6;
        xs[c * 65 + t] = x[(((size_t)b * C_ + c) * V_ + v) * T_ + t];
    }
    __syncthreads();
    for (int i = tid; i < 16384; i += 256) {
        const int c = i & 255, t = i >> 8;
        xT[(((size_t)b * V_ + v) * T_ + t) * C_ + c] = f2bf(xs[c * 65 + t]);
    }
}

// ---------------------------------------------------------------------------
// pack_weights: wq/wk/wv -> Wqkv bf16 [192][2304], wo -> Wo bf16 [256][1152].
// K order: (c_chunk, tap, c_within32).
// ---------------------------------------------------------------------------
__global__ __launch_bounds__(256) void pack_weights(
    const float* __restrict__ wq, const float* __restrict__ wk,
    const float* __restrict__ wv, const float* __restrict__ wo,
    ushort* __restrict__ Wqkv, ushort* __restrict__ Wo)
{
    const int r = blockIdx.x;
    const int tid = threadIdx.x;
    const float* src; ushort* dst; int Klen;
    if (r < 192) {
        if (r < 32)      src = wq + (size_t)r * 2304;
        else if (r < 64) src = wk + (size_t)(r - 32) * 2304;
        else             src = wv + (size_t)(r - 64) * 2304;
        dst = Wqkv + (size_t)r * 2304; Klen = 2304;
    } else {
        src = wo + (size_t)(r - 192) * 1152;
        dst = Wo + (size_t)(r - 192) * 1152; Klen = 1152;
    }
    for (int k = tid; k < Klen; k += 256) {
        const int cc = k / 288, rem = k % 288;
        const int tap = rem >> 5, ci = rem & 31;
        const int c = cc * 32 + ci;
        dst[k] = f2bf(src[c * 9 + tap]);
    }
}

// ---------------------------------------------------------------------------
// conv_qkv_mfma: implicit-GEMM 3x3 conv, bf16 MFMA 16x16x32.
// R3: register-prefetch software pipeline (T14). Per K-step: issue next
// tile's global loads into regs BEFORE compute; ds_write them at the top of
// the next iteration. Global latency hides under the 72-MFMA compute phase;
// the serialized region per K-step shrinks to {2 barriers + 13 ds_writes}.
// Halo zero-pad rows of Bs are written once before the loop (invariant).
// ---------------------------------------------------------------------------
__global__ __launch_bounds__(256) void conv_qkv_mfma(
    const ushort* __restrict__ xT, const ushort* __restrict__ Wqkv,
    ushort* __restrict__ qb, ushort* __restrict__ kb, ushort* __restrict__ vb)
{
    __shared__ __align__(16) ushort Bs[4 * 66 * 40];   // 21.1 KB
    __shared__ __align__(16) ushort As[64 * 296];      // 37.9 KB

    const int tid  = threadIdx.x;
    const int lane = tid & 63;
    const int wave = tid >> 6;
    const int wave_m = (wave >> 1) * 32;
    const int wave_n = (wave & 1) * 64;
    const int nl = lane & 15;
    const int q8 = lane >> 4;

    int idx = blockIdx.x;
    const int og = idx % 3; idx /= 3;
    const int v2 = idx & 127;
    const int b  = idx >> 7;
    const int v0 = v2 * 2;

    floatx4 acc[2][4];
    #pragma unroll
    for (int i = 0; i < 2; i++)
        #pragma unroll
        for (int j = 0; j < 4; j++) acc[i][j] = (floatx4)0.f;

    const int rr = tid >> 6, ts = tid & 63;
    const int vsrc = v0 - 1 + rr;
    const int ar = tid >> 2, sub = tid & 3;
    const bool bvalid = (vsrc >= 0 && vsrc < V_);   // wave-uniform

    const ushort* bsrc_base =
        &xT[(((size_t)b * V_ + (bvalid ? vsrc : 0)) * T_ + ts) * C_];
    const ushort* asrc_base = &Wqkv[(size_t)(og * 64 + ar) * 2304];
    ushort* const bdst = &Bs[(rr * 66 + 1 + ts) * 40];
    ushort* const adst = &As[ar * 296];

    // one-time halo zero pads (columns t=-1 and t=64 of each staged v-row)
    if (tid < 8) {
        const int r2 = tid >> 1, side = (tid & 1) * 65;
        ushort* zp = &Bs[(r2 * 66 + side) * 40];
        const uint4 z = {0u, 0u, 0u, 0u};
        *(uint4*)(zp + 0) = z; *(uint4*)(zp + 8) = z;
        *(uint4*)(zp + 16) = z; *(uint4*)(zp + 24) = z;
    }

    // prefetch K-step 0 into registers
    uint4 bpre[4];
    uint4 apre[9];
    {
        const uint4 z = {0u, 0u, 0u, 0u};
        #pragma unroll
        for (int j = 0; j < 4; j++)
            bpre[j] = bvalid ? *(const uint4*)(bsrc_base + j * 8) : z;
        #pragma unroll
        for (int j = 0; j < 9; j++)
            apre[j] = *(const uint4*)(asrc_base + (sub + j * 4) * 8);
    }

    for (int cc = 0; cc < 8; cc++) {
        __syncthreads();               // previous compute done -> LDS free
        // commit prefetched tile to LDS
        *(uint4*)(bdst + 0)  = bpre[0];
        *(uint4*)(bdst + 8)  = bpre[1];
        *(uint4*)(bdst + 16) = bpre[2];
        *(uint4*)(bdst + 24) = bpre[3];
        #pragma unroll
        for (int j = 0; j < 9; j++)
            *(uint4*)(adst + (sub + j * 4) * 8) = apre[j];
        __syncthreads();

        // issue next tile's global loads (latency hides under compute below)
        if (cc < 7) {
            const uint4 z = {0u, 0u, 0u, 0u};
            const ushort* bsrc = bsrc_base + (cc + 1) * 32;
            #pragma unroll
            for (int j = 0; j < 4; j++)
                bpre[j] = bvalid ? *(const uint4*)(bsrc + j * 8) : z;
            const ushort* asrc = asrc_base + (cc + 1) * 288;
            #pragma unroll
            for (int j = 0; j < 9; j++)
                apre[j] = *(const uint4*)(asrc + (sub + j * 4) * 8);
        }

        #pragma unroll
        for (int tap = 0; tap < 9; tap++) {
            const int dv = tap / 3, dt = tap % 3;
            const bf16x8 a0 = *(const bf16x8*)&As[(wave_m + nl) * 296 + tap * 32 + q8 * 8];
            const bf16x8 a1 = *(const bf16x8*)&As[(wave_m + 16 + nl) * 296 + tap * 32 + q8 * 8];
            #pragma unroll
            for (int nt = 0; nt < 4; nt++) {
                const int n0 = wave_n + nt * 16;
                const int vv = n0 >> 6, tt0 = n0 & 63;
                const bf16x8 bf = *(const bf16x8*)
                    &Bs[((vv + dv) * 66 + tt0 + nl + dt) * 40 + q8 * 8];
                acc[0][nt] = __builtin_amdgcn_mfma_f32_16x16x32_bf16(a0, bf, acc[0][nt], 0, 0, 0);
                acc[1][nt] = __builtin_amdgcn_mfma_f32_16x16x32_bf16(a1, bf, acc[1][nt], 0, 0, 0);
            }
        }
    }

    #pragma unroll
    for (int mt = 0; mt < 2; mt++) {
        const int g0 = og * 64 + wave_m + mt * 16 + q8 * 4;
        ushort* buf; int cbase, Cb;
        if (g0 < 32)      { buf = qb; cbase = g0;      Cb = CQ_; }
        else if (g0 < 64) { buf = kb; cbase = g0 - 32; Cb = CQ_; }
        else              { buf = vb; cbase = g0 - 64; Cb = C1_; }
        #pragma unroll
        for (int nt = 0; nt < 4; nt++) {
            const int n = wave_n + nt * 16 + nl;
            const int vv = n >> 6, tt = n & 63;
            const floatx4 A = acc[mt][nt];
            ushort4 o;
            o.x = f2bf(A[0]); o.y = f2bf(A[1]); o.z = f2bf(A[2]); o.w = f2bf(A[3]);
            *(ushort4*)&buf[(((size_t)b * V_ + v0 + vv) * T_ + tt) * Cb + cbase] = o;
        }
    }
}

// ---------------------------------------------------------------------------
// conv_o_mfma: same register-prefetch pipeline as conv_qkv (4 K-steps).
// ---------------------------------------------------------------------------
__global__ __launch_bounds__(256) void conv_o_mfma(
    const ushort* __restrict__ avT, const ushort* __restrict__ Wo,
    const float* __restrict__ x, const float* __restrict__ sigma,
    float* __restrict__ out)
{
    __shared__ __align__(16) ushort Bs[4 * 66 * 40];
    __shared__ __align__(16) ushort As[64 * 296];

    const int tid  = threadIdx.x;
    const int lane = tid & 63;
    const int wave = tid >> 6;
    const int wave_m = (wave >> 1) * 32;
    const int wave_n = (wave & 1) * 64;
    const int nl = lane & 15;
    const int q8 = lane >> 4;

    int idx = blockIdx.x;
    const int og = idx & 3; idx >>= 2;
    const int v2 = idx & 127;
    const int b  = idx >> 7;
    const int v0 = v2 * 2;

    floatx4 acc[2][4];
    #pragma unroll
    for (int i = 0; i < 2; i++)
        #pragma unroll
        for (int j = 0; j < 4; j++) acc[i][j] = (floatx4)0.f;

    const int rr = tid >> 6, ts = tid & 63;
    const int vsrc = v0 - 1 + rr;
    const int ar = tid >> 2, sub = tid & 3;
    const bool bvalid = (vsrc >= 0 && vsrc < V_);   // wave-uniform

    const ushort* bsrc_base =
        &avT[(((size_t)b * V_ + (bvalid ? vsrc : 0)) * T_ + ts) * C1_];
    const ushort* asrc_base = &Wo[(size_t)(og * 64 + ar) * 1152];
    ushort* const bdst = &Bs[(rr * 66 + 1 + ts) * 40];
    ushort* const adst = &As[ar * 296];

    if (tid < 8) {
        const int r2 = tid >> 1, side = (tid & 1) * 65;
        ushort* zp = &Bs[(r2 * 66 + side) * 40];
        const uint4 z = {0u, 0u, 0u, 0u};
        *(uint4*)(zp + 0) = z; *(uint4*)(zp + 8) = z;
        *(uint4*)(zp + 16) = z; *(uint4*)(zp + 24) = z;
    }

    uint4 bpre[4];
    uint4 apre[9];
    {
        const uint4 z = {0u, 0u, 0u, 0u};
        #pragma unroll
        for (int j = 0; j < 4; j++)
            bpre[j] = bvalid ? *(const uint4*)(bsrc_base + j * 8) : z;
        #pragma unroll
        for (int j = 0; j < 9; j++)
            apre[j] = *(const uint4*)(asrc_base + (sub + j * 4) * 8);
    }

    for (int cc = 0; cc < 4; cc++) {
        __syncthreads();
        *(uint4*)(bdst + 0)  = bpre[0];
        *(uint4*)(bdst + 8)  = bpre[1];
        *(uint4*)(bdst + 16) = bpre[2];
        *(uint4*)(bdst + 24) = bpre[3];
        #pragma unroll
        for (int j = 0; j < 9; j++)
            *(uint4*)(adst + (sub + j * 4) * 8) = apre[j];
        __syncthreads();

        if (cc < 3) {
            const uint4 z = {0u, 0u, 0u, 0u};
            const ushort* bsrc = bsrc_base + (cc + 1) * 32;
            #pragma unroll
            for (int j = 0; j < 4; j++)
                bpre[j] = bvalid ? *(const uint4*)(bsrc + j * 8) : z;
            const ushort* asrc = asrc_base + (cc + 1) * 288;
            #pragma unroll
            for (int j = 0; j < 9; j++)
                apre[j] = *(const uint4*)(asrc + (sub + j * 4) * 8);
        }

        #pragma unroll
        for (int tap = 0; tap < 9; tap++) {
            const int dv = tap / 3, dt = tap % 3;
            const bf16x8 a0 = *(const bf16x8*)&As[(wave_m + nl) * 296 + tap * 32 + q8 * 8];
            const bf16x8 a1 = *(const bf16x8*)&As[(wave_m + 16 + nl) * 296 + tap * 32 + q8 * 8];
            #pragma unroll
            for (int nt = 0; nt < 4; nt++) {
                const int n0 = wave_n + nt * 16;
                const int vv = n0 >> 6, tt0 = n0 & 63;
                const bf16x8 bf = *(const bf16x8*)
                    &Bs[((vv + dv) * 66 + tt0 + nl + dt) * 40 + q8 * 8];
                acc[0][nt] = __builtin_amdgcn_mfma_f32_16x16x32_bf16(a0, bf, acc[0][nt], 0, 0, 0);
                acc[1][nt] = __builtin_amdgcn_mfma_f32_16x16x32_bf16(a1, bf, acc[1][nt], 0, 0, 0);
            }
        }
    }

    const float sg = sigma[0];
    #pragma unroll
    for (int mt = 0; mt < 2; mt++) {
        const int cb = og * 64 + wave_m + mt * 16 + q8 * 4;
        #pragma unroll
        for (int nt = 0; nt < 4; nt++) {
            const int n = wave_n + nt * 16 + nl;
            const int vv = n >> 6, tt = n & 63;
            const floatx4 A = acc[mt][nt];
            #pragma unroll
            for (int r = 0; r < 4; r++) {
                const size_t o = (((size_t)b * C_ + cb + r) * V_ + (v0 + vv)) * T_ + tt;
                out[o] = x[o] + sg * A[r];
            }
        }
    }
}

// ---------------------------------------------------------------------------
// attn_mfma: flash-style MFMA attention, one block per (b,t) slice.
// (unchanged this round)
// ---------------------------------------------------------------------------
#define L2E 1.44269504f

__global__ __launch_bounds__(256, 1) void attn_mfma(
    const ushort* __restrict__ qb, const ushort* __restrict__ kb,
    const ushort* __restrict__ vb, ushort* __restrict__ avT)
{
    __shared__ __align__(16) ushort Ksh[256 * 40];     // 20.5 KB
    __shared__ __align__(16) ushort Vt[128 * 264];     // 67.6 KB (swizzled)
    __shared__ __align__(16) ushort Psh[4][64 * 72];   // 36.9 KB

    const int tid  = threadIdx.x;
    const int lane = tid & 63;
    const int w    = tid >> 6;
    const int l15  = lane & 15;
    const int q8   = lane >> 4;
    const int bt = blockIdx.x;
    const int b = bt >> 6, t = bt & 63;

    // ---- stage K slice: Ksh[u][c], row pad 40 halves ----
    {
        const ushort* kp = &kb[(((size_t)b * 256 + tid) * 64 + t) * 32];
        #pragma unroll
        for (int j = 0; j < 4; j++)
            *(uint4*)&Ksh[tid * 40 + j * 8] = *(const uint4*)(kp + j * 8);
    }
    // ---- stage V^T: Vt[c][u], 16B-u-block swizzled ----
    {
        const int c8 = tid & 15;                 // channel group of 8
        #pragma unroll
        for (int it = 0; it < 8; it++) {
            const int up = it * 16 + (tid >> 4); // u-pair 0..127
            const ushort* vp0 = &vb[(((size_t)b * 256 + up * 2) * 64 + t) * 128 + c8 * 8];
            uint4 ra = *(const uint4*)vp0;
            uint4 rb = *(const uint4*)(vp0 + 64 * 128);
            const ushort* pa = (const ushort*)&ra;
            const ushort* pb = (const ushort*)&rb;
            const int g = up >> 2, sub = up & 3;
            #pragma unroll
            for (int j = 0; j < 8; j++) {
                const int c = c8 * 8 + j;
                const uint word = (uint)pa[j] | ((uint)pb[j] << 16);
                *(uint*)((char*)(Vt + c * 264) + ((g ^ (c8 & 7)) * 16 + sub * 4)) = word;
            }
        }
    }
    // ---- Q fragments (loop-invariant) ----
    bf16x8 qf[4];
    #pragma unroll
    for (int vt = 0; vt < 4; vt++) {
        const int v = w * 64 + vt * 16 + l15;
        qf[vt] = *(const bf16x8*)&qb[(((size_t)b * 256 + v) * 64 + t) * 32 + q8 * 8];
    }
    __syncthreads();

    floatx4 accO[8][4];
    #pragma unroll
    for (int ct = 0; ct < 8; ct++)
        #pragma unroll
        for (int vt = 0; vt < 4; vt++) accO[ct][vt] = (floatx4)0.f;
    float m2[4] = {-3e38f, -3e38f, -3e38f, -3e38f};
    float lr[4] = {0.f, 0.f, 0.f, 0.f};
    ushort* Pw = Psh[w];

    for (int ch = 0; ch < 4; ch++) {
        const int u0 = ch * 64;
        // ---- S^T chunk: 16 tiles [ut][vt] ----
        floatx4 s[4][4];
        #pragma unroll
        for (int ut = 0; ut < 4; ut++) {
            const bf16x8 kf = *(const bf16x8*)&Ksh[(u0 + ut * 16 + l15) * 40 + q8 * 8];
            #pragma unroll
            for (int vt = 0; vt < 4; vt++) {
                floatx4 z = (floatx4)0.f;
                s[ut][vt] = __builtin_amdgcn_mfma_f32_16x16x32_bf16(kf, qf[vt], z, 0, 0, 0);
            }
        }
        // ---- online softmax per column v (log2 domain) ----
        #pragma unroll
        for (int vt = 0; vt < 4; vt++) {
            #pragma unroll
            for (int ut = 0; ut < 4; ut++)
                #pragma unroll
                for (int r = 0; r < 4; r++) s[ut][vt][r] *= L2E;
            float cm = -3e38f;
            #pragma unroll
            for (int ut = 0; ut < 4; ut++)
                #pragma unroll
                for (int r = 0; r < 4; r++) cm = fmaxf(cm, s[ut][vt][r]);
            cm = fmaxf(cm, __shfl_xor(cm, 16));
            cm = fmaxf(cm, __shfl_xor(cm, 32));
            const float mn = fmaxf(m2[vt], cm);
            const float alpha = __builtin_amdgcn_exp2f(m2[vt] - mn);
            float csum = 0.f;
            #pragma unroll
            for (int ut = 0; ut < 4; ut++)
                #pragma unroll
                for (int r = 0; r < 4; r++) {
                    const float p = __builtin_amdgcn_exp2f(s[ut][vt][r] - mn);
                    s[ut][vt][r] = p;
                    csum += p;
                }
            csum += __shfl_xor(csum, 16);
            csum += __shfl_xor(csum, 32);
            lr[vt] = lr[vt] * alpha + csum;
            m2[vt] = mn;
            #pragma unroll
            for (int ct = 0; ct < 8; ct++)
                #pragma unroll
                for (int r = 0; r < 4; r++) accO[ct][vt][r] *= alpha;
            // pack P -> Psh[v][u_local] (bf16)
            const int vrow = vt * 16 + l15;
            #pragma unroll
            for (int ut = 0; ut < 4; ut++) {
                const uint w01 = (uint)f2bf(s[ut][vt][0]) | ((uint)f2bf(s[ut][vt][1]) << 16);
                const uint w23 = (uint)f2bf(s[ut][vt][2]) | ((uint)f2bf(s[ut][vt][3]) << 16);
                ushort* pp = Pw + vrow * 72 + ut * 16 + q8 * 4;
                *(uint*)pp = w01;
                *(uint*)(pp + 2) = w23;
            }
        }
        // ---- PV: accO[ct][vt] += Vt_frag * P_frag ----
        #pragma unroll
        for (int kc = 0; kc < 2; kc++) {
            bf16x8 pf[4];
            #pragma unroll
            for (int vt = 0; vt < 4; vt++)
                pf[vt] = *(const bf16x8*)&Pw[(vt * 16 + l15) * 72 + kc * 32 + q8 * 8];
            #pragma unroll
            for (int ct = 0; ct < 8; ct++) {
                const int c = ct * 16 + l15;
                const int ublk = (u0 + kc * 32) / 8 + q8;
                const bf16x8 vf = *(const bf16x8*)
                    ((const char*)(Vt + c * 264) + ((ublk ^ ((c >> 3) & 7)) * 16));
                #pragma unroll
                for (int vt = 0; vt < 4; vt++)
                    accO[ct][vt] = __builtin_amdgcn_mfma_f32_16x16x32_bf16(vf, pf[vt], accO[ct][vt], 0, 0, 0);
            }
        }
    }

    // ---- epilogue: normalize, restage via Psh, coalesced 128B stores ----
    float inv[4];
    #pragma unroll
    for (int vt = 0; vt < 4; vt++) inv[vt] = 1.f / lr[vt];

    #pragma unroll
    for (int half = 0; half < 2; half++) {
        #pragma unroll
        for (int ct4 = 0; ct4 < 4; ct4++) {
            const int ct = half * 4 + ct4;
            #pragma unroll
            for (int vt = 0; vt < 4; vt++) {
                ushort4 o;
                o.x = f2bf(accO[ct][vt][0] * inv[vt]);
                o.y = f2bf(accO[ct][vt][1] * inv[vt]);
                o.z = f2bf(accO[ct][vt][2] * inv[vt]);
                o.w = f2bf(accO[ct][vt][3] * inv[vt]);
                *(ushort4*)&Pw[(vt * 16 + l15) * 72 + ct4 * 16 + q8 * 4] = o;
            }
        }
        // wave-local: lane v copies its 64-channel half-row out (128B)
        const size_t dst = (((size_t)b * 256 + w * 64 + lane) * 64 + t) * 128 + half * 64;
        #pragma unroll
        for (int j = 0; j < 8; j++)
            *(uint4*)&avT[dst + j * 8] = *(const uint4*)&Pw[lane * 72 + j * 8];
    }
}

// ---------------------------------------------------------------------------
extern "C" void kernel_launch(void* const* d_in, const int* in_sizes, int n_in,
                              void* d_out, int out_size, void* d_ws, size_t ws_size,
                              hipStream_t stream)
{
    const float* x     = (const float*)d_in[0];
    const float* wq    = (const float*)d_in[1];
    const float* wk    = (const float*)d_in[2];
    const float* wv    = (const float*)d_in[3];
    const float* wo    = (const float*)d_in[4];
    const float* sigma = (const float*)d_in[5];
    float* out = (float*)d_out;

    // workspace (bf16/ushort), total ~152.5 MB
    ushort* ws   = (ushort*)d_ws;
    ushort* xT   = ws;  ws += (size_t)B_ * V_ * T_ * C_;    // 33,554,432
    ushort* qb   = ws;  ws += (size_t)B_ * V_ * T_ * CQ_;   //  4,194,304
    ushort* kb   = ws;  ws += (size_t)B_ * V_ * T_ * CQ_;   //  4,194,304
    ushort* vb   = ws;  ws += (size_t)B_ * V_ * T_ * C1_;   // 16,777,216
    ushort* avT  = ws;  ws += (size_t)B_ * V_ * T_ * C1_;   // 16,777,216
    ushort* Wqkv = ws;  ws += 192 * 2304;
    ushort* Wo   = ws;  ws += 256 * 1152;

    transpose_x <<<B_ * V_, 256, 0, stream>>>(x, xT);
    pack_weights<<<448, 256, 0, stream>>>(wq, wk, wv, wo, Wqkv, Wo);
    conv_qkv_mfma<<<B_ * 128 * 3, 256, 0, stream>>>(xT, Wqkv, qb, kb, vb);
    attn_mfma   <<<B_ * T_, 256, 0, stream>>>(qb, kb, vb, avT);
    conv_o_mfma <<<B_ * 128 * 4, 256, 0, stream>>>(avT, Wo, x, sigma, out);
}

// Round 2
// 552.368 us; speedup vs baseline: 1.8332x; 1.8332x over previous
//
#include <hip/hip_runtime.h>
#include <hip/hip_bf16.h>
#include <cstdint>

// Problem dims (fixed by reference)
#define B_  8
#define C_  256
#define V_  256
#define T_  64
#define CQ_ 32
#define C1_ 128

typedef float  floatx4 __attribute__((ext_vector_type(4)));
typedef __bf16 bf16x8  __attribute__((ext_vector_type(8)));

static __device__ __forceinline__ ushort f2bf(float f) {
    union { float f; uint32_t u; } cv; cv.f = f;
    const uint32_t u = cv.u;
    return (ushort)((u + 0x7FFFu + ((u >> 16) & 1u)) >> 16);   // RNE
}

// ---------------------------------------------------------------------------
// transpose_x: x fp32 [B,C,V,T] -> xT bf16 [B,V,T,C] (channel-contiguous)
// ---------------------------------------------------------------------------
__global__ __launch_bounds__(256) void transpose_x(
    const float* __restrict__ x, ushort* __restrict__ xT)
{
    __shared__ float xs[256 * 65];   // [c][t], row pad 65 -> conflict-free
    const int tid = threadIdx.x;
    const int v = blockIdx.x & 255;
    const int b = blockIdx.x >> 8;

    for (int i = tid; i < 16384; i += 256) {
        const int t = i & 63, c = i >> 6;
        xs[c * 65 + t] = x[(((size_t)b * C_ + c) * V_ + v) * T_ + t];
    }
    __syncthreads();
    for (int i = tid; i < 16384; i += 256) {
        const int c = i & 255, t = i >> 8;
        xT[(((size_t)b * V_ + v) * T_ + t) * C_ + c] = f2bf(xs[c * 65 + t]);
    }
}

// ---------------------------------------------------------------------------
// pack_weights: wq/wk/wv -> Wqkv bf16 [192][2304], wo -> Wo bf16 [256][1152].
// K order: (c_chunk, tap, c_within32).
// ---------------------------------------------------------------------------
__global__ __launch_bounds__(256) void pack_weights(
    const float* __restrict__ wq, const float* __restrict__ wk,
    const float* __restrict__ wv, const float* __restrict__ wo,
    ushort* __restrict__ Wqkv, ushort* __restrict__ Wo)
{
    const int r = blockIdx.x;
    const int tid = threadIdx.x;
    const float* src; ushort* dst; int Klen;
    if (r < 192) {
        if (r < 32)      src = wq + (size_t)r * 2304;
        else if (r < 64) src = wk + (size_t)(r - 32) * 2304;
        else             src = wv + (size_t)(r - 64) * 2304;
        dst = Wqkv + (size_t)r * 2304; Klen = 2304;
    } else {
        src = wo + (size_t)(r - 192) * 1152;
        dst = Wo + (size_t)(r - 192) * 1152; Klen = 1152;
    }
    for (int k = tid; k < Klen; k += 256) {
        const int cc = k / 288, rem = k % 288;
        const int tap = rem >> 5, ci = rem & 31;
        const int c = cc * 32 + ci;
        dst[k] = f2bf(src[c * 9 + tap]);
    }
}

// ---------------------------------------------------------------------------
// conv_qkv_mfma: implicit-GEMM 3x3 conv, bf16 MFMA 16x16x32.
// R4: register-prefetch pipeline with NAMED SCALAR uint4s (R3's arrays were
// demoted: bpre[4] -> promote-alloca-to-LDS (+16KB LDS), apre[9] -> scratch
// (1 GB/dispatch HBM writes). Named scalars cannot form an alloca, so the
// prefetch state must live in VGPRs (~+52 VGPR).
// Per K-step: ds_write prefetched regs -> barrier -> issue next global loads
// -> 72 MFMA (hides load latency) -> barrier.
// ---------------------------------------------------------------------------
__global__ __launch_bounds__(256) void conv_qkv_mfma(
    const ushort* __restrict__ xT, const ushort* __restrict__ Wqkv,
    ushort* __restrict__ qb, ushort* __restrict__ kb, ushort* __restrict__ vb)
{
    __shared__ __align__(16) ushort Bs[4 * 66 * 40];   // 21.1 KB
    __shared__ __align__(16) ushort As[64 * 296];      // 37.9 KB

    const int tid  = threadIdx.x;
    const int lane = tid & 63;
    const int wave = tid >> 6;
    const int wave_m = (wave >> 1) * 32;
    const int wave_n = (wave & 1) * 64;
    const int nl = lane & 15;
    const int q8 = lane >> 4;

    int idx = blockIdx.x;
    const int og = idx % 3; idx /= 3;
    const int v2 = idx & 127;
    const int b  = idx >> 7;
    const int v0 = v2 * 2;

    floatx4 acc[2][4];
    #pragma unroll
    for (int i = 0; i < 2; i++)
        #pragma unroll
        for (int j = 0; j < 4; j++) acc[i][j] = (floatx4)0.f;

    const int rr = tid >> 6, ts = tid & 63;
    const int vsrc = v0 - 1 + rr;
    const int ar = tid >> 2, sub = tid & 3;
    const bool bvalid = (vsrc >= 0 && vsrc < V_);   // wave-uniform

    const ushort* bsrc_base =
        &xT[(((size_t)b * V_ + (bvalid ? vsrc : 0)) * T_ + ts) * C_];
    const ushort* asrc_base = &Wqkv[(size_t)(og * 64 + ar) * 2304];
    ushort* const bdst = &Bs[(rr * 66 + 1 + ts) * 40];
    ushort* const adst = &As[ar * 296];

    // one-time halo zero pads (columns t=-1 and t=64 of each staged v-row)
    if (tid < 8) {
        const int r2 = tid >> 1, side = (tid & 1) * 65;
        ushort* zp = &Bs[(r2 * 66 + side) * 40];
        const uint4 z = {0u, 0u, 0u, 0u};
        *(uint4*)(zp + 0) = z; *(uint4*)(zp + 8) = z;
        *(uint4*)(zp + 16) = z; *(uint4*)(zp + 24) = z;
    }

    const uint4 z4 = {0u, 0u, 0u, 0u};
    // named scalar prefetch state (MUST stay in VGPRs — no arrays!)
    uint4 bp0, bp1, bp2, bp3;
    uint4 ap0, ap1, ap2, ap3, ap4, ap5, ap6, ap7, ap8;

#define QKV_PREFETCH(CCN)                                                    \
    do {                                                                     \
        const ushort* bs_ = bsrc_base + (CCN) * 32;                          \
        bp0 = bvalid ? *(const uint4*)(bs_ + 0)  : z4;                       \
        bp1 = bvalid ? *(const uint4*)(bs_ + 8)  : z4;                       \
        bp2 = bvalid ? *(const uint4*)(bs_ + 16) : z4;                       \
        bp3 = bvalid ? *(const uint4*)(bs_ + 24) : z4;                       \
        const ushort* as_ = asrc_base + (CCN) * 288;                         \
        ap0 = *(const uint4*)(as_ + (sub + 0)  * 8);                         \
        ap1 = *(const uint4*)(as_ + (sub + 4)  * 8);                         \
        ap2 = *(const uint4*)(as_ + (sub + 8)  * 8);                         \
        ap3 = *(const uint4*)(as_ + (sub + 12) * 8);                         \
        ap4 = *(const uint4*)(as_ + (sub + 16) * 8);                         \
        ap5 = *(const uint4*)(as_ + (sub + 20) * 8);                         \
        ap6 = *(const uint4*)(as_ + (sub + 24) * 8);                         \
        ap7 = *(const uint4*)(as_ + (sub + 28) * 8);                         \
        ap8 = *(const uint4*)(as_ + (sub + 32) * 8);                         \
    } while (0)

    QKV_PREFETCH(0);

    for (int cc = 0; cc < 8; cc++) {
        __syncthreads();               // previous compute done -> LDS free
        // commit prefetched tile to LDS
        *(uint4*)(bdst + 0)  = bp0;
        *(uint4*)(bdst + 8)  = bp1;
        *(uint4*)(bdst + 16) = bp2;
        *(uint4*)(bdst + 24) = bp3;
        *(uint4*)(adst + (sub + 0)  * 8) = ap0;
        *(uint4*)(adst + (sub + 4)  * 8) = ap1;
        *(uint4*)(adst + (sub + 8)  * 8) = ap2;
        *(uint4*)(adst + (sub + 12) * 8) = ap3;
        *(uint4*)(adst + (sub + 16) * 8) = ap4;
        *(uint4*)(adst + (sub + 20) * 8) = ap5;
        *(uint4*)(adst + (sub + 24) * 8) = ap6;
        *(uint4*)(adst + (sub + 28) * 8) = ap7;
        *(uint4*)(adst + (sub + 32) * 8) = ap8;
        __syncthreads();

        // issue next tile's global loads (latency hides under compute below)
        if (cc < 7) {
            QKV_PREFETCH(cc + 1);
        }

        #pragma unroll
        for (int tap = 0; tap < 9; tap++) {
            const int dv = tap / 3, dt = tap % 3;
            const bf16x8 a0 = *(const bf16x8*)&As[(wave_m + nl) * 296 + tap * 32 + q8 * 8];
            const bf16x8 a1 = *(const bf16x8*)&As[(wave_m + 16 + nl) * 296 + tap * 32 + q8 * 8];
            #pragma unroll
            for (int nt = 0; nt < 4; nt++) {
                const int n0 = wave_n + nt * 16;
                const int vv = n0 >> 6, tt0 = n0 & 63;
                const bf16x8 bf = *(const bf16x8*)
                    &Bs[((vv + dv) * 66 + tt0 + nl + dt) * 40 + q8 * 8];
                acc[0][nt] = __builtin_amdgcn_mfma_f32_16x16x32_bf16(a0, bf, acc[0][nt], 0, 0, 0);
                acc[1][nt] = __builtin_amdgcn_mfma_f32_16x16x32_bf16(a1, bf, acc[1][nt], 0, 0, 0);
            }
        }
    }
#undef QKV_PREFETCH

    #pragma unroll
    for (int mt = 0; mt < 2; mt++) {
        const int g0 = og * 64 + wave_m + mt * 16 + q8 * 4;
        ushort* buf; int cbase, Cb;
        if (g0 < 32)      { buf = qb; cbase = g0;      Cb = CQ_; }
        else if (g0 < 64) { buf = kb; cbase = g0 - 32; Cb = CQ_; }
        else              { buf = vb; cbase = g0 - 64; Cb = C1_; }
        #pragma unroll
        for (int nt = 0; nt < 4; nt++) {
            const int n = wave_n + nt * 16 + nl;
            const int vv = n >> 6, tt = n & 63;
            const floatx4 A = acc[mt][nt];
            ushort4 o;
            o.x = f2bf(A[0]); o.y = f2bf(A[1]); o.z = f2bf(A[2]); o.w = f2bf(A[3]);
            *(ushort4*)&buf[(((size_t)b * V_ + v0 + vv) * T_ + tt) * Cb + cbase] = o;
        }
    }
}

// ---------------------------------------------------------------------------
// conv_o_mfma: same named-scalar register-prefetch pipeline (4 K-steps).
// ---------------------------------------------------------------------------
__global__ __launch_bounds__(256) void conv_o_mfma(
    const ushort* __restrict__ avT, const ushort* __restrict__ Wo,
    const float* __restrict__ x, const float* __restrict__ sigma,
    float* __restrict__ out)
{
    __shared__ __align__(16) ushort Bs[4 * 66 * 40];
    __shared__ __align__(16) ushort As[64 * 296];

    const int tid  = threadIdx.x;
    const int lane = tid & 63;
    const int wave = tid >> 6;
    const int wave_m = (wave >> 1) * 32;
    const int wave_n = (wave & 1) * 64;
    const int nl = lane & 15;
    const int q8 = lane >> 4;

    int idx = blockIdx.x;
    const int og = idx & 3; idx >>= 2;
    const int v2 = idx & 127;
    const int b  = idx >> 7;
    const int v0 = v2 * 2;

    floatx4 acc[2][4];
    #pragma unroll
    for (int i = 0; i < 2; i++)
        #pragma unroll
        for (int j = 0; j < 4; j++) acc[i][j] = (floatx4)0.f;

    const int rr = tid >> 6, ts = tid & 63;
    const int vsrc = v0 - 1 + rr;
    const int ar = tid >> 2, sub = tid & 3;
    const bool bvalid = (vsrc >= 0 && vsrc < V_);   // wave-uniform

    const ushort* bsrc_base =
        &avT[(((size_t)b * V_ + (bvalid ? vsrc : 0)) * T_ + ts) * C1_];
    const ushort* asrc_base = &Wo[(size_t)(og * 64 + ar) * 1152];
    ushort* const bdst = &Bs[(rr * 66 + 1 + ts) * 40];
    ushort* const adst = &As[ar * 296];

    if (tid < 8) {
        const int r2 = tid >> 1, side = (tid & 1) * 65;
        ushort* zp = &Bs[(r2 * 66 + side) * 40];
        const uint4 z = {0u, 0u, 0u, 0u};
        *(uint4*)(zp + 0) = z; *(uint4*)(zp + 8) = z;
        *(uint4*)(zp + 16) = z; *(uint4*)(zp + 24) = z;
    }

    const uint4 z4 = {0u, 0u, 0u, 0u};
    uint4 bp0, bp1, bp2, bp3;
    uint4 ap0, ap1, ap2, ap3, ap4, ap5, ap6, ap7, ap8;

#define O_PREFETCH(CCN)                                                      \
    do {                                                                     \
        const ushort* bs_ = bsrc_base + (CCN) * 32;                          \
        bp0 = bvalid ? *(const uint4*)(bs_ + 0)  : z4;                       \
        bp1 = bvalid ? *(const uint4*)(bs_ + 8)  : z4;                       \
        bp2 = bvalid ? *(const uint4*)(bs_ + 16) : z4;                       \
        bp3 = bvalid ? *(const uint4*)(bs_ + 24) : z4;                       \
        const ushort* as_ = asrc_base + (CCN) * 288;                         \
        ap0 = *(const uint4*)(as_ + (sub + 0)  * 8);                         \
        ap1 = *(const uint4*)(as_ + (sub + 4)  * 8);                         \
        ap2 = *(const uint4*)(as_ + (sub + 8)  * 8);                         \
        ap3 = *(const uint4*)(as_ + (sub + 12) * 8);                         \
        ap4 = *(const uint4*)(as_ + (sub + 16) * 8);                         \
        ap5 = *(const uint4*)(as_ + (sub + 20) * 8);                         \
        ap6 = *(const uint4*)(as_ + (sub + 24) * 8);                         \
        ap7 = *(const uint4*)(as_ + (sub + 28) * 8);                         \
        ap8 = *(const uint4*)(as_ + (sub + 32) * 8);                         \
    } while (0)

    O_PREFETCH(0);

    for (int cc = 0; cc < 4; cc++) {
        __syncthreads();
        *(uint4*)(bdst + 0)  = bp0;
        *(uint4*)(bdst + 8)  = bp1;
        *(uint4*)(bdst + 16) = bp2;
        *(uint4*)(bdst + 24) = bp3;
        *(uint4*)(adst + (sub + 0)  * 8) = ap0;
        *(uint4*)(adst + (sub + 4)  * 8) = ap1;
        *(uint4*)(adst + (sub + 8)  * 8) = ap2;
        *(uint4*)(adst + (sub + 12) * 8) = ap3;
        *(uint4*)(adst + (sub + 16) * 8) = ap4;
        *(uint4*)(adst + (sub + 20) * 8) = ap5;
        *(uint4*)(adst + (sub + 24) * 8) = ap6;
        *(uint4*)(adst + (sub + 28) * 8) = ap7;
        *(uint4*)(adst + (sub + 32) * 8) = ap8;
        __syncthreads();

        if (cc < 3) {
            O_PREFETCH(cc + 1);
        }

        #pragma unroll
        for (int tap = 0; tap < 9; tap++) {
            const int dv = tap / 3, dt = tap % 3;
            const bf16x8 a0 = *(const bf16x8*)&As[(wave_m + nl) * 296 + tap * 32 + q8 * 8];
            const bf16x8 a1 = *(const bf16x8*)&As[(wave_m + 16 + nl) * 296 + tap * 32 + q8 * 8];
            #pragma unroll
            for (int nt = 0; nt < 4; nt++) {
                const int n0 = wave_n + nt * 16;
                const int vv = n0 >> 6, tt0 = n0 & 63;
                const bf16x8 bf = *(const bf16x8*)
                    &Bs[((vv + dv) * 66 + tt0 + nl + dt) * 40 + q8 * 8];
                acc[0][nt] = __builtin_amdgcn_mfma_f32_16x16x32_bf16(a0, bf, acc[0][nt], 0, 0, 0);
                acc[1][nt] = __builtin_amdgcn_mfma_f32_16x16x32_bf16(a1, bf, acc[1][nt], 0, 0, 0);
            }
        }
    }
#undef O_PREFETCH

    const float sg = sigma[0];
    #pragma unroll
    for (int mt = 0; mt < 2; mt++) {
        const int cb = og * 64 + wave_m + mt * 16 + q8 * 4;
        #pragma unroll
        for (int nt = 0; nt < 4; nt++) {
            const int n = wave_n + nt * 16 + nl;
            const int vv = n >> 6, tt = n & 63;
            const floatx4 A = acc[mt][nt];
            #pragma unroll
            for (int r = 0; r < 4; r++) {
                const size_t o = (((size_t)b * C_ + cb + r) * V_ + (v0 + vv)) * T_ + tt;
                out[o] = x[o] + sg * A[r];
            }
        }
    }
}

// ---------------------------------------------------------------------------
// attn_mfma: flash-style MFMA attention, one block per (b,t) slice.
// (unchanged this round)
// ---------------------------------------------------------------------------
#define L2E 1.44269504f

__global__ __launch_bounds__(256, 1) void attn_mfma(
    const ushort* __restrict__ qb, const ushort* __restrict__ kb,
    const ushort* __restrict__ vb, ushort* __restrict__ avT)
{
    __shared__ __align__(16) ushort Ksh[256 * 40];     // 20.5 KB
    __shared__ __align__(16) ushort Vt[128 * 264];     // 67.6 KB (swizzled)
    __shared__ __align__(16) ushort Psh[4][64 * 72];   // 36.9 KB

    const int tid  = threadIdx.x;
    const int lane = tid & 63;
    const int w    = tid >> 6;
    const int l15  = lane & 15;
    const int q8   = lane >> 4;
    const int bt = blockIdx.x;
    const int b = bt >> 6, t = bt & 63;

    // ---- stage K slice: Ksh[u][c], row pad 40 halves ----
    {
        const ushort* kp = &kb[(((size_t)b * 256 + tid) * 64 + t) * 32];
        #pragma unroll
        for (int j = 0; j < 4; j++)
            *(uint4*)&Ksh[tid * 40 + j * 8] = *(const uint4*)(kp + j * 8);
    }
    // ---- stage V^T: Vt[c][u], 16B-u-block swizzled ----
    {
        const int c8 = tid & 15;                 // channel group of 8
        #pragma unroll
        for (int it = 0; it < 8; it++) {
            const int up = it * 16 + (tid >> 4); // u-pair 0..127
            const ushort* vp0 = &vb[(((size_t)b * 256 + up * 2) * 64 + t) * 128 + c8 * 8];
            uint4 ra = *(const uint4*)vp0;
            uint4 rb = *(const uint4*)(vp0 + 64 * 128);
            const ushort* pa = (const ushort*)&ra;
            const ushort* pb = (const ushort*)&rb;
            const int g = up >> 2, sub = up & 3;
            #pragma unroll
            for (int j = 0; j < 8; j++) {
                const int c = c8 * 8 + j;
                const uint word = (uint)pa[j] | ((uint)pb[j] << 16);
                *(uint*)((char*)(Vt + c * 264) + ((g ^ (c8 & 7)) * 16 + sub * 4)) = word;
            }
        }
    }
    // ---- Q fragments (loop-invariant) ----
    bf16x8 qf[4];
    #pragma unroll
    for (int vt = 0; vt < 4; vt++) {
        const int v = w * 64 + vt * 16 + l15;
        qf[vt] = *(const bf16x8*)&qb[(((size_t)b * 256 + v) * 64 + t) * 32 + q8 * 8];
    }
    __syncthreads();

    floatx4 accO[8][4];
    #pragma unroll
    for (int ct = 0; ct < 8; ct++)
        #pragma unroll
        for (int vt = 0; vt < 4; vt++) accO[ct][vt] = (floatx4)0.f;
    float m2[4] = {-3e38f, -3e38f, -3e38f, -3e38f};
    float lr[4] = {0.f, 0.f, 0.f, 0.f};
    ushort* Pw = Psh[w];

    for (int ch = 0; ch < 4; ch++) {
        const int u0 = ch * 64;
        // ---- S^T chunk: 16 tiles [ut][vt] ----
        floatx4 s[4][4];
        #pragma unroll
        for (int ut = 0; ut < 4; ut++) {
            const bf16x8 kf = *(const bf16x8*)&Ksh[(u0 + ut * 16 + l15) * 40 + q8 * 8];
            #pragma unroll
            for (int vt = 0; vt < 4; vt++) {
                floatx4 z = (floatx4)0.f;
                s[ut][vt] = __builtin_amdgcn_mfma_f32_16x16x32_bf16(kf, qf[vt], z, 0, 0, 0);
            }
        }
        // ---- online softmax per column v (log2 domain) ----
        #pragma unroll
        for (int vt = 0; vt < 4; vt++) {
            #pragma unroll
            for (int ut = 0; ut < 4; ut++)
                #pragma unroll
                for (int r = 0; r < 4; r++) s[ut][vt][r] *= L2E;
            float cm = -3e38f;
            #pragma unroll
            for (int ut = 0; ut < 4; ut++)
                #pragma unroll
                for (int r = 0; r < 4; r++) cm = fmaxf(cm, s[ut][vt][r]);
            cm = fmaxf(cm, __shfl_xor(cm, 16));
            cm = fmaxf(cm, __shfl_xor(cm, 32));
            const float mn = fmaxf(m2[vt], cm);
            const float alpha = __builtin_amdgcn_exp2f(m2[vt] - mn);
            float csum = 0.f;
            #pragma unroll
            for (int ut = 0; ut < 4; ut++)
                #pragma unroll
                for (int r = 0; r < 4; r++) {
                    const float p = __builtin_amdgcn_exp2f(s[ut][vt][r] - mn);
                    s[ut][vt][r] = p;
                    csum += p;
                }
            csum += __shfl_xor(csum, 16);
            csum += __shfl_xor(csum, 32);
            lr[vt] = lr[vt] * alpha + csum;
            m2[vt] = mn;
            #pragma unroll
            for (int ct = 0; ct < 8; ct++)
                #pragma unroll
                for (int r = 0; r < 4; r++) accO[ct][vt][r] *= alpha;
            // pack P -> Psh[v][u_local] (bf16)
            const int vrow = vt * 16 + l15;
            #pragma unroll
            for (int ut = 0; ut < 4; ut++) {
                const uint w01 = (uint)f2bf(s[ut][vt][0]) | ((uint)f2bf(s[ut][vt][1]) << 16);
                const uint w23 = (uint)f2bf(s[ut][vt][2]) | ((uint)f2bf(s[ut][vt][3]) << 16);
                ushort* pp = Pw + vrow * 72 + ut * 16 + q8 * 4;
                *(uint*)pp = w01;
                *(uint*)(pp + 2) = w23;
            }
        }
        // ---- PV: accO[ct][vt] += Vt_frag * P_frag ----
        #pragma unroll
        for (int kc = 0; kc < 2; kc++) {
            bf16x8 pf[4];
            #pragma unroll
            for (int vt = 0; vt < 4; vt++)
                pf[vt] = *(const bf16x8*)&Pw[(vt * 16 + l15) * 72 + kc * 32 + q8 * 8];
            #pragma unroll
            for (int ct = 0; ct < 8; ct++) {
                const int c = ct * 16 + l15;
                const int ublk = (u0 + kc * 32) / 8 + q8;
                const bf16x8 vf = *(const bf16x8*)
                    ((const char*)(Vt + c * 264) + ((ublk ^ ((c >> 3) & 7)) * 16));
                #pragma unroll
                for (int vt = 0; vt < 4; vt++)
                    accO[ct][vt] = __builtin_amdgcn_mfma_f32_16x16x32_bf16(vf, pf[vt], accO[ct][vt], 0, 0, 0);
            }
        }
    }

    // ---- epilogue: normalize, restage via Psh, coalesced 128B stores ----
    float inv[4];
    #pragma unroll
    for (int vt = 0; vt < 4; vt++) inv[vt] = 1.f / lr[vt];

    #pragma unroll
    for (int half = 0; half < 2; half++) {
        #pragma unroll
        for (int ct4 = 0; ct4 < 4; ct4++) {
            const int ct = half * 4 + ct4;
            #pragma unroll
            for (int vt = 0; vt < 4; vt++) {
                ushort4 o;
                o.x = f2bf(accO[ct][vt][0] * inv[vt]);
                o.y = f2bf(accO[ct][vt][1] * inv[vt]);
                o.z = f2bf(accO[ct][vt][2] * inv[vt]);
                o.w = f2bf(accO[ct][vt][3] * inv[vt]);
                *(ushort4*)&Pw[(vt * 16 + l15) * 72 + ct4 * 16 + q8 * 4] = o;
            }
        }
        // wave-local: lane v copies its 64-channel half-row out (128B)
        const size_t dst = (((size_t)b * 256 + w * 64 + lane) * 64 + t) * 128 + half * 64;
        #pragma unroll
        for (int j = 0; j < 8; j++)
            *(uint4*)&avT[dst + j * 8] = *(const uint4*)&Pw[lane * 72 + j * 8];
    }
}

// ---------------------------------------------------------------------------
extern "C" void kernel_launch(void* const* d_in, const int* in_sizes, int n_in,
                              void* d_out, int out_size, void* d_ws, size_t ws_size,
                              hipStream_t stream)
{
    const float* x     = (const float*)d_in[0];
    const float* wq    = (const float*)d_in[1];
    const float* wk    = (const float*)d_in[2];
    const float* wv    = (const float*)d_in[3];
    const float* wo    = (const float*)d_in[4];
    const float* sigma = (const float*)d_in[5];
    float* out = (float*)d_out;

    // workspace (bf16/ushort), total ~152.5 MB
    ushort* ws   = (ushort*)d_ws;
    ushort* xT   = ws;  ws += (size_t)B_ * V_ * T_ * C_;    // 33,554,432
    ushort* qb   = ws;  ws += (size_t)B_ * V_ * T_ * CQ_;   //  4,194,304
    ushort* kb   = ws;  ws += (size_t)B_ * V_ * T_ * CQ_;   //  4,194,304
    ushort* vb   = ws;  ws += (size_t)B_ * V_ * T_ * C1_;   // 16,777,216
    ushort* avT  = ws;  ws += (size_t)B_ * V_ * T_ * C1_;   // 16,777,216
    ushort* Wqkv = ws;  ws += 192 * 2304;
    ushort* Wo   = ws;  ws += 256 * 1152;

    transpose_x <<<B_ * V_, 256, 0, stream>>>(x, xT);
    pack_weights<<<448, 256, 0, stream>>>(wq, wk, wv, wo, Wqkv, Wo);
    conv_qkv_mfma<<<B_ * 128 * 3, 256, 0, stream>>>(xT, Wqkv, qb, kb, vb);
    attn_mfma   <<<B_ * T_, 256, 0, stream>>>(qb, kb, vb, avT);
    conv_o_mfma <<<B_ * 128 * 4, 256, 0, stream>>>(avT, Wo, x, sigma, out);
}

// Round 4
// 504.627 us; speedup vs baseline: 2.0067x; 1.0946x over previous
//
#include <hip/hip_runtime.h>
#include <hip/hip_bf16.h>
#include <cstdint>

// Problem dims (fixed by reference)
#define B_  8
#define C_  256
#define V_  256
#define T_  64
#define CQ_ 32
#define C1_ 128

typedef float  floatx4 __attribute__((ext_vector_type(4)));
typedef __bf16 bf16x8  __attribute__((ext_vector_type(8)));

static __device__ __forceinline__ ushort f2bf(float f) {
    union { float f; uint32_t u; } cv; cv.f = f;
    const uint32_t u = cv.u;
    return (ushort)((u + 0x7FFFu + ((u >> 16) & 1u)) >> 16);   // RNE
}

// ---------------------------------------------------------------------------
// transpose_x: x fp32 [B,C,V,T] -> xT bf16 [B,V,T,C] (channel-contiguous)
// ---------------------------------------------------------------------------
__global__ __launch_bounds__(256) void transpose_x(
    const float* __restrict__ x, ushort* __restrict__ xT)
{
    __shared__ float xs[256 * 65];   // [c][t], row pad 65 -> conflict-free
    const int tid = threadIdx.x;
    const int v = blockIdx.x & 255;
    const int b = blockIdx.x >> 8;

    for (int i = tid; i < 16384; i += 256) {
        const int t = i & 63, c = i >> 6;
        xs[c * 65 + t] = x[(((size_t)b * C_ + c) * V_ + v) * T_ + t];
    }
    __syncthreads();
    for (int i = tid; i < 16384; i += 256) {
        const int c = i & 255, t = i >> 8;
        xT[(((size_t)b * V_ + v) * T_ + t) * C_ + c] = f2bf(xs[c * 65 + t]);
    }
}

// ---------------------------------------------------------------------------
// pack_weights (R5): emit weights in exact MFMA A-fragment order so conv
// kernels load frags DIRECTLY from global (1KB coalesced wave loads, L2/L1
// resident) — no LDS staging for A.
// Wqkv packed: [og=3][cc=8][tap=9][mtile=4][lane=64][e=8]  (442368 ushorts)
// Wo   packed: [og=4][cc=4][tap=9][mtile=4][lane=64][e=8]  (294912 ushorts)
// element = W[row = og*64 + mtile*16 + (lane&15)][c = cc*32 + (lane>>4)*8+e][tap]
// ---------------------------------------------------------------------------
__global__ __launch_bounds__(256) void pack_weights(
    const float* __restrict__ wq, const float* __restrict__ wk,
    const float* __restrict__ wv, const float* __restrict__ wo,
    ushort* __restrict__ Wqkv, ushort* __restrict__ Wo)
{
    const int tid = blockIdx.x * 256 + threadIdx.x;
    const int total1 = 442368, total2 = 294912;
    for (int idx = tid; idx < total1 + total2; idx += gridDim.x * 256) {
        if (idx < total1) {
            int i = idx;
            const int e = i & 7;      i >>= 3;
            const int lane = i & 63;  i >>= 6;
            const int mtile = i & 3;  i >>= 2;
            const int tap = i % 9;    i /= 9;
            const int cc = i & 7;
            const int og = i >> 3;
            const int r = og * 64 + mtile * 16 + (lane & 15);
            const int c = cc * 32 + (lane >> 4) * 8 + e;
            const float* srow;
            if (r < 32)      srow = wq + (size_t)r * 2304;
            else if (r < 64) srow = wk + (size_t)(r - 32) * 2304;
            else             srow = wv + (size_t)(r - 64) * 2304;
            Wqkv[idx] = f2bf(srow[c * 9 + tap]);
        } else {
            int i = idx - total1;
            const int e = i & 7;      i >>= 3;
            const int lane = i & 63;  i >>= 6;
            const int mtile = i & 3;  i >>= 2;
            const int tap = i % 9;    i /= 9;
            const int cc = i & 3;
            const int og = i >> 2;
            const int r = og * 64 + mtile * 16 + (lane & 15);
            const int c = cc * 32 + (lane >> 4) * 8 + e;
            Wo[idx - total1] = f2bf(wo[(size_t)r * 1152 + c * 9 + tap]);
        }
    }
}

// ---------------------------------------------------------------------------
// conv_qkv_mfma (R5): implicit-GEMM 3x3 conv, bf16 MFMA 16x16x32.
// Block = 64M x 256N (4 v-rows x 64 t); wave w owns v-row v0+w, all 64 M rows.
// A-frags read directly from frag-packed global (L2/L1) — no As in LDS.
// B (x tile) staged in LDS: 6 v-rows (4 + halo), pitch 40 -> conflict-free.
// Per wave per K-step: 36 global A-loads + 36 LDS B-reads -> 144 MFMAs
// (B reuse 4x, A reuse 4x). LDS/block-step = 168KB (was 269KB at half tile).
// Named-scalar B prefetch pipeline kept from R4.
// Block index: og slowest so co-resident blocks share the same weight slab.
// ---------------------------------------------------------------------------
__global__ __launch_bounds__(256) void conv_qkv_mfma(
    const ushort* __restrict__ xT, const ushort* __restrict__ Wqkv,
    ushort* __restrict__ qb, ushort* __restrict__ kb, ushort* __restrict__ vb)
{
    __shared__ __align__(16) ushort Bs[6 * 66 * 40];   // 31.7 KB

    const int tid  = threadIdx.x;
    const int lane = tid & 63;
    const int w    = tid >> 6;          // wave owns v-row v0 + w
    const int nl   = lane & 15;
    const int q8   = lane >> 4;

    const int og  = blockIdx.x >> 9;    // 0..2
    const int rem = blockIdx.x & 511;
    const int vg  = rem >> 3;           // 0..63
    const int b   = rem & 7;
    const int v0  = vg * 4;

    floatx4 acc[4][4];                  // [mt][nt]
    #pragma unroll
    for (int i = 0; i < 4; i++)
        #pragma unroll
        for (int j = 0; j < 4; j++) acc[i][j] = (floatx4)0.f;

    const int t4 = tid >> 2, c4 = tid & 3;   // thread stages (row k, t=t4, c-chunk c4)
    ushort* const bdst = &Bs[(1 + t4) * 40 + c4 * 8];
    const ushort* const xb  = &xT[(((size_t)b * V_) * T_ + t4) * C_ + c4 * 8];
    const ushort* const Wog = Wqkv + (size_t)og * 147456 + lane * 8;

    // one-time halo zeros (t=-1 and t=64 for all 6 staged rows)
    if (tid < 12) {
        const int r = tid >> 1, side = (tid & 1) * 65;
        ushort* zp = &Bs[(r * 66 + side) * 40];
        const uint4 z = {0u, 0u, 0u, 0u};
        *(uint4*)(zp + 0) = z; *(uint4*)(zp + 8) = z;
        *(uint4*)(zp + 16) = z; *(uint4*)(zp + 24) = z;
    }

    const uint4 z4 = {0u, 0u, 0u, 0u};
    uint4 s0, s1, s2, s3, s4, s5;       // named scalars -> must stay in VGPRs

#define QPF(CC) do {                                                          \
    const int co_ = (CC) * 32;                                                \
    s0 = (v0 >= 1)  ? *(const uint4*)(xb + (size_t)(v0 - 1) * (T_ * C_) + co_) : z4; \
    s1 =              *(const uint4*)(xb + (size_t)(v0    ) * (T_ * C_) + co_);      \
    s2 =              *(const uint4*)(xb + (size_t)(v0 + 1) * (T_ * C_) + co_);      \
    s3 =              *(const uint4*)(xb + (size_t)(v0 + 2) * (T_ * C_) + co_);      \
    s4 =              *(const uint4*)(xb + (size_t)(v0 + 3) * (T_ * C_) + co_);      \
    s5 = (v0 < 252) ? *(const uint4*)(xb + (size_t)(v0 + 4) * (T_ * C_) + co_) : z4; \
} while (0)

    QPF(0);

    for (int cc = 0; cc < 8; cc++) {
        __syncthreads();                // previous compute done -> LDS free
        *(uint4*)(bdst + 0 * 2640) = s0;
        *(uint4*)(bdst + 1 * 2640) = s1;
        *(uint4*)(bdst + 2 * 2640) = s2;
        *(uint4*)(bdst + 3 * 2640) = s3;
        *(uint4*)(bdst + 4 * 2640) = s4;
        *(uint4*)(bdst + 5 * 2640) = s5;
        __syncthreads();
        if (cc < 7) QPF(cc + 1);        // next-tile loads hide under compute

        const ushort* const Wcc = Wog + cc * 18432;
        #pragma unroll
        for (int tap = 0; tap < 9; tap++) {
            const int dv = tap / 3, dt = tap % 3;
            bf16x8 bfr[4];
            #pragma unroll
            for (int nt = 0; nt < 4; nt++)
                bfr[nt] = *(const bf16x8*)
                    &Bs[((w + dv) * 66 + nt * 16 + nl + dt) * 40 + q8 * 8];
            const bf16x8 a0 = *(const bf16x8*)(Wcc + tap * 2048 + 0 * 512);
            const bf16x8 a1 = *(const bf16x8*)(Wcc + tap * 2048 + 1 * 512);
            const bf16x8 a2 = *(const bf16x8*)(Wcc + tap * 2048 + 2 * 512);
            const bf16x8 a3 = *(const bf16x8*)(Wcc + tap * 2048 + 3 * 512);
            #pragma unroll
            for (int nt = 0; nt < 4; nt++) {
                acc[0][nt] = __builtin_amdgcn_mfma_f32_16x16x32_bf16(a0, bfr[nt], acc[0][nt], 0, 0, 0);
                acc[1][nt] = __builtin_amdgcn_mfma_f32_16x16x32_bf16(a1, bfr[nt], acc[1][nt], 0, 0, 0);
                acc[2][nt] = __builtin_amdgcn_mfma_f32_16x16x32_bf16(a2, bfr[nt], acc[2][nt], 0, 0, 0);
                acc[3][nt] = __builtin_amdgcn_mfma_f32_16x16x32_bf16(a3, bfr[nt], acc[3][nt], 0, 0, 0);
            }
        }
    }
#undef QPF

    #pragma unroll
    for (int mt = 0; mt < 4; mt++) {
        const int g0 = og * 64 + mt * 16 + q8 * 4;
        ushort* buf; int cbase, Cb;
        if (g0 < 32)      { buf = qb; cbase = g0;      Cb = CQ_; }
        else if (g0 < 64) { buf = kb; cbase = g0 - 32; Cb = CQ_; }
        else              { buf = vb; cbase = g0 - 64; Cb = C1_; }
        #pragma unroll
        for (int nt = 0; nt < 4; nt++) {
            const int tt = nt * 16 + nl;
            const floatx4 A = acc[mt][nt];
            ushort4 o;
            o.x = f2bf(A[0]); o.y = f2bf(A[1]); o.z = f2bf(A[2]); o.w = f2bf(A[3]);
            *(ushort4*)&buf[(((size_t)b * V_ + v0 + w) * T_ + tt) * Cb + cbase] = o;
        }
    }
}

// ---------------------------------------------------------------------------
// conv_o_mfma (R5): same structure; 4 K-steps, 128 input channels, residual.
// ---------------------------------------------------------------------------
__global__ __launch_bounds__(256) void conv_o_mfma(
    const ushort* __restrict__ avT, const ushort* __restrict__ Wo,
    const float* __restrict__ x, const float* __restrict__ sigma,
    float* __restrict__ out)
{
    __shared__ __align__(16) ushort Bs[6 * 66 * 40];   // 31.7 KB

    const int tid  = threadIdx.x;
    const int lane = tid & 63;
    const int w    = tid >> 6;
    const int nl   = lane & 15;
    const int q8   = lane >> 4;

    const int og  = blockIdx.x >> 9;    // 0..3
    const int rem = blockIdx.x & 511;
    const int vg  = rem >> 3;
    const int b   = rem & 7;
    const int v0  = vg * 4;

    floatx4 acc[4][4];
    #pragma unroll
    for (int i = 0; i < 4; i++)
        #pragma unroll
        for (int j = 0; j < 4; j++) acc[i][j] = (floatx4)0.f;

    const int t4 = tid >> 2, c4 = tid & 3;
    ushort* const bdst = &Bs[(1 + t4) * 40 + c4 * 8];
    const ushort* const ab  = &avT[(((size_t)b * V_) * T_ + t4) * C1_ + c4 * 8];
    const ushort* const Wog = Wo + (size_t)og * 73728 + lane * 8;

    if (tid < 12) {
        const int r = tid >> 1, side = (tid & 1) * 65;
        ushort* zp = &Bs[(r * 66 + side) * 40];
        const uint4 z = {0u, 0u, 0u, 0u};
        *(uint4*)(zp + 0) = z; *(uint4*)(zp + 8) = z;
        *(uint4*)(zp + 16) = z; *(uint4*)(zp + 24) = z;
    }

    const uint4 z4 = {0u, 0u, 0u, 0u};
    uint4 s0, s1, s2, s3, s4, s5;

#define OPF(CC) do {                                                          \
    const int co_ = (CC) * 32;                                                \
    s0 = (v0 >= 1)  ? *(const uint4*)(ab + (size_t)(v0 - 1) * (T_ * C1_) + co_) : z4; \
    s1 =              *(const uint4*)(ab + (size_t)(v0    ) * (T_ * C1_) + co_);      \
    s2 =              *(const uint4*)(ab + (size_t)(v0 + 1) * (T_ * C1_) + co_);      \
    s3 =              *(const uint4*)(ab + (size_t)(v0 + 2) * (T_ * C1_) + co_);      \
    s4 =              *(const uint4*)(ab + (size_t)(v0 + 3) * (T_ * C1_) + co_);      \
    s5 = (v0 < 252) ? *(const uint4*)(ab + (size_t)(v0 + 4) * (T_ * C1_) + co_) : z4; \
} while (0)

    OPF(0);

    for (int cc = 0; cc < 4; cc++) {
        __syncthreads();
        *(uint4*)(bdst + 0 * 2640) = s0;
        *(uint4*)(bdst + 1 * 2640) = s1;
        *(uint4*)(bdst + 2 * 2640) = s2;
        *(uint4*)(bdst + 3 * 2640) = s3;
        *(uint4*)(bdst + 4 * 2640) = s4;
        *(uint4*)(bdst + 5 * 2640) = s5;
        __syncthreads();
        if (cc < 3) OPF(cc + 1);

        const ushort* const Wcc = Wog + cc * 18432;
        #pragma unroll
        for (int tap = 0; tap < 9; tap++) {
            const int dv = tap / 3, dt = tap % 3;
            bf16x8 bfr[4];
            #pragma unroll
            for (int nt = 0; nt < 4; nt++)
                bfr[nt] = *(const bf16x8*)
                    &Bs[((w + dv) * 66 + nt * 16 + nl + dt) * 40 + q8 * 8];
            const bf16x8 a0 = *(const bf16x8*)(Wcc + tap * 2048 + 0 * 512);
            const bf16x8 a1 = *(const bf16x8*)(Wcc + tap * 2048 + 1 * 512);
            const bf16x8 a2 = *(const bf16x8*)(Wcc + tap * 2048 + 2 * 512);
            const bf16x8 a3 = *(const bf16x8*)(Wcc + tap * 2048 + 3 * 512);
            #pragma unroll
            for (int nt = 0; nt < 4; nt++) {
                acc[0][nt] = __builtin_amdgcn_mfma_f32_16x16x32_bf16(a0, bfr[nt], acc[0][nt], 0, 0, 0);
                acc[1][nt] = __builtin_amdgcn_mfma_f32_16x16x32_bf16(a1, bfr[nt], acc[1][nt], 0, 0, 0);
                acc[2][nt] = __builtin_amdgcn_mfma_f32_16x16x32_bf16(a2, bfr[nt], acc[2][nt], 0, 0, 0);
                acc[3][nt] = __builtin_amdgcn_mfma_f32_16x16x32_bf16(a3, bfr[nt], acc[3][nt], 0, 0, 0);
            }
        }
    }
#undef OPF

    const float sg = sigma[0];
    #pragma unroll
    for (int mt = 0; mt < 4; mt++) {
        const int cb = og * 64 + mt * 16 + q8 * 4;
        #pragma unroll
        for (int nt = 0; nt < 4; nt++) {
            const int tt = nt * 16 + nl;
            const floatx4 A = acc[mt][nt];
            #pragma unroll
            for (int r = 0; r < 4; r++) {
                const size_t o = (((size_t)b * C_ + cb + r) * V_ + (v0 + w)) * T_ + tt;
                out[o] = x[o] + sg * A[r];
            }
        }
    }
}

// ---------------------------------------------------------------------------
// attn_mfma: flash-style MFMA attention, one block per (b,t) slice.
// (unchanged this round)
// ---------------------------------------------------------------------------
#define L2E 1.44269504f

__global__ __launch_bounds__(256, 1) void attn_mfma(
    const ushort* __restrict__ qb, const ushort* __restrict__ kb,
    const ushort* __restrict__ vb, ushort* __restrict__ avT)
{
    __shared__ __align__(16) ushort Ksh[256 * 40];     // 20.5 KB
    __shared__ __align__(16) ushort Vt[128 * 264];     // 67.6 KB (swizzled)
    __shared__ __align__(16) ushort Psh[4][64 * 72];   // 36.9 KB

    const int tid  = threadIdx.x;
    const int lane = tid & 63;
    const int w    = tid >> 6;
    const int l15  = lane & 15;
    const int q8   = lane >> 4;
    const int bt = blockIdx.x;
    const int b = bt >> 6, t = bt & 63;

    // ---- stage K slice: Ksh[u][c], row pad 40 halves ----
    {
        const ushort* kp = &kb[(((size_t)b * 256 + tid) * 64 + t) * 32];
        #pragma unroll
        for (int j = 0; j < 4; j++)
            *(uint4*)&Ksh[tid * 40 + j * 8] = *(const uint4*)(kp + j * 8);
    }
    // ---- stage V^T: Vt[c][u], 16B-u-block swizzled ----
    {
        const int c8 = tid & 15;                 // channel group of 8
        #pragma unroll
        for (int it = 0; it < 8; it++) {
            const int up = it * 16 + (tid >> 4); // u-pair 0..127
            const ushort* vp0 = &vb[(((size_t)b * 256 + up * 2) * 64 + t) * 128 + c8 * 8];
            uint4 ra = *(const uint4*)vp0;
            uint4 rb = *(const uint4*)(vp0 + 64 * 128);
            const ushort* pa = (const ushort*)&ra;
            const ushort* pb = (const ushort*)&rb;
            const int g = up >> 2, sub = up & 3;
            #pragma unroll
            for (int j = 0; j < 8; j++) {
                const int c = c8 * 8 + j;
                const uint word = (uint)pa[j] | ((uint)pb[j] << 16);
                *(uint*)((char*)(Vt + c * 264) + ((g ^ (c8 & 7)) * 16 + sub * 4)) = word;
            }
        }
    }
    // ---- Q fragments (loop-invariant) ----
    bf16x8 qf[4];
    #pragma unroll
    for (int vt = 0; vt < 4; vt++) {
        const int v = w * 64 + vt * 16 + l15;
        qf[vt] = *(const bf16x8*)&qb[(((size_t)b * 256 + v) * 64 + t) * 32 + q8 * 8];
    }
    __syncthreads();

    floatx4 accO[8][4];
    #pragma unroll
    for (int ct = 0; ct < 8; ct++)
        #pragma unroll
        for (int vt = 0; vt < 4; vt++) accO[ct][vt] = (floatx4)0.f;
    float m2[4] = {-3e38f, -3e38f, -3e38f, -3e38f};
    float lr[4] = {0.f, 0.f, 0.f, 0.f};
    ushort* Pw = Psh[w];

    for (int ch = 0; ch < 4; ch++) {
        const int u0 = ch * 64;
        // ---- S^T chunk: 16 tiles [ut][vt] ----
        floatx4 s[4][4];
        #pragma unroll
        for (int ut = 0; ut < 4; ut++) {
            const bf16x8 kf = *(const bf16x8*)&Ksh[(u0 + ut * 16 + l15) * 40 + q8 * 8];
            #pragma unroll
            for (int vt = 0; vt < 4; vt++) {
                floatx4 z = (floatx4)0.f;
                s[ut][vt] = __builtin_amdgcn_mfma_f32_16x16x32_bf16(kf, qf[vt], z, 0, 0, 0);
            }
        }
        // ---- online softmax per column v (log2 domain) ----
        #pragma unroll
        for (int vt = 0; vt < 4; vt++) {
            #pragma unroll
            for (int ut = 0; ut < 4; ut++)
                #pragma unroll
                for (int r = 0; r < 4; r++) s[ut][vt][r] *= L2E;
            float cm = -3e38f;
            #pragma unroll
            for (int ut = 0; ut < 4; ut++)
                #pragma unroll
                for (int r = 0; r < 4; r++) cm = fmaxf(cm, s[ut][vt][r]);
            cm = fmaxf(cm, __shfl_xor(cm, 16));
            cm = fmaxf(cm, __shfl_xor(cm, 32));
            const float mn = fmaxf(m2[vt], cm);
            const float alpha = __builtin_amdgcn_exp2f(m2[vt] - mn);
            float csum = 0.f;
            #pragma unroll
            for (int ut = 0; ut < 4; ut++)
                #pragma unroll
                for (int r = 0; r < 4; r++) {
                    const float p = __builtin_amdgcn_exp2f(s[ut][vt][r] - mn);
                    s[ut][vt][r] = p;
                    csum += p;
                }
            csum += __shfl_xor(csum, 16);
            csum += __shfl_xor(csum, 32);
            lr[vt] = lr[vt] * alpha + csum;
            m2[vt] = mn;
            #pragma unroll
            for (int ct = 0; ct < 8; ct++)
                #pragma unroll
                for (int r = 0; r < 4; r++) accO[ct][vt][r] *= alpha;
            // pack P -> Psh[v][u_local] (bf16)
            const int vrow = vt * 16 + l15;
            #pragma unroll
            for (int ut = 0; ut < 4; ut++) {
                const uint w01 = (uint)f2bf(s[ut][vt][0]) | ((uint)f2bf(s[ut][vt][1]) << 16);
                const uint w23 = (uint)f2bf(s[ut][vt][2]) | ((uint)f2bf(s[ut][vt][3]) << 16);
                ushort* pp = Pw + vrow * 72 + ut * 16 + q8 * 4;
                *(uint*)pp = w01;
                *(uint*)(pp + 2) = w23;
            }
        }
        // ---- PV: accO[ct][vt] += Vt_frag * P_frag ----
        #pragma unroll
        for (int kc = 0; kc < 2; kc++) {
            bf16x8 pf[4];
            #pragma unroll
            for (int vt = 0; vt < 4; vt++)
                pf[vt] = *(const bf16x8*)&Pw[(vt * 16 + l15) * 72 + kc * 32 + q8 * 8];
            #pragma unroll
            for (int ct = 0; ct < 8; ct++) {
                const int c = ct * 16 + l15;
                const int ublk = (u0 + kc * 32) / 8 + q8;
                const bf16x8 vf = *(const bf16x8*)
                    ((const char*)(Vt + c * 264) + ((ublk ^ ((c >> 3) & 7)) * 16));
                #pragma unroll
                for (int vt = 0; vt < 4; vt++)
                    accO[ct][vt] = __builtin_amdgcn_mfma_f32_16x16x32_bf16(vf, pf[vt], accO[ct][vt], 0, 0, 0);
            }
        }
    }

    // ---- epilogue: normalize, restage via Psh, coalesced 128B stores ----
    float inv[4];
    #pragma unroll
    for (int vt = 0; vt < 4; vt++) inv[vt] = 1.f / lr[vt];

    #pragma unroll
    for (int half = 0; half < 2; half++) {
        #pragma unroll
        for (int ct4 = 0; ct4 < 4; ct4++) {
            const int ct = half * 4 + ct4;
            #pragma unroll
            for (int vt = 0; vt < 4; vt++) {
                ushort4 o;
                o.x = f2bf(accO[ct][vt][0] * inv[vt]);
                o.y = f2bf(accO[ct][vt][1] * inv[vt]);
                o.z = f2bf(accO[ct][vt][2] * inv[vt]);
                o.w = f2bf(accO[ct][vt][3] * inv[vt]);
                *(ushort4*)&Pw[(vt * 16 + l15) * 72 + ct4 * 16 + q8 * 4] = o;
            }
        }
        // wave-local: lane v copies its 64-channel half-row out (128B)
        const size_t dst = (((size_t)b * 256 + w * 64 + lane) * 64 + t) * 128 + half * 64;
        #pragma unroll
        for (int j = 0; j < 8; j++)
            *(uint4*)&avT[dst + j * 8] = *(const uint4*)&Pw[lane * 72 + j * 8];
    }
}

// ---------------------------------------------------------------------------
extern "C" void kernel_launch(void* const* d_in, const int* in_sizes, int n_in,
                              void* d_out, int out_size, void* d_ws, size_t ws_size,
                              hipStream_t stream)
{
    const float* x     = (const float*)d_in[0];
    const float* wq    = (const float*)d_in[1];
    const float* wk    = (const float*)d_in[2];
    const float* wv    = (const float*)d_in[3];
    const float* wo    = (const float*)d_in[4];
    const float* sigma = (const float*)d_in[5];
    float* out = (float*)d_out;

    // workspace (bf16/ushort), total ~152.5 MB
    ushort* ws   = (ushort*)d_ws;
    ushort* xT   = ws;  ws += (size_t)B_ * V_ * T_ * C_;    // 33,554,432
    ushort* qb   = ws;  ws += (size_t)B_ * V_ * T_ * CQ_;   //  4,194,304
    ushort* kb   = ws;  ws += (size_t)B_ * V_ * T_ * CQ_;   //  4,194,304
    ushort* vb   = ws;  ws += (size_t)B_ * V_ * T_ * C1_;   // 16,777,216
    ushort* avT  = ws;  ws += (size_t)B_ * V_ * T_ * C1_;   // 16,777,216
    ushort* Wqkv = ws;  ws += 442368;                       // frag-packed
    ushort* Wo   = ws;  ws += 294912;                       // frag-packed

    transpose_x <<<B_ * V_, 256, 0, stream>>>(x, xT);
    pack_weights<<<448, 256, 0, stream>>>(wq, wk, wv, wo, Wqkv, Wo);
    conv_qkv_mfma<<<3 * 512, 256, 0, stream>>>(xT, Wqkv, qb, kb, vb);
    attn_mfma   <<<B_ * T_, 256, 0, stream>>>(qb, kb, vb, avT);
    conv_o_mfma <<<4 * 512, 256, 0, stream>>>(avT, Wo, x, sigma, out);
}